// Round 8
// baseline (85.073 us; speedup 1.0000x reference)
//
#include <hip/hip_runtime.h>

#define ROWS   681408        // 64 * 10647
#define NBINS  8192
#define CAP    64            // bucket capacity per bin
#define TOPK   192
#define SELCAP 256

// ws word offsets
#define WS_ROW0     4        // 6 floats: score, class, x1,y1,x2,y2
#define WS_CNT      16       // 8192 uints -> words 16..8207 (16B aligned)
#define WS_BUCKET   8448     // uint2[NBINS*CAP] -> 1,048,576 words (4 MB)

__device__ __forceinline__ float clip01(float v) {
    return fminf(fmaxf(v, 0.0f), 1.0f);
}

__global__ void init_kernel(unsigned int* __restrict__ ws) {
    int i = blockIdx.x * 256 + threadIdx.x;
    if (i < NBINS) ws[WS_CNT + i] = 0u;
}

__global__ __launch_bounds__(256) void decode_kernel(
    const float* __restrict__ y, unsigned int* __restrict__ ws)
{
    const int row = blockIdx.x * 256 + threadIdx.x;
    if (row >= ROWS) return;

    const float*  p  = y + (size_t)row * 85;
    const float4* p4 = (const float4*)p;   // base 4-mod-16; gfx9 tolerates dword align

    // whole row in one lane: elems 0..3 = box, 4 = conf, 5..84 = probs.
    float4 f0 = p4[0];
    float4 f1 = p4[1];
    const float cf = f1.x;

    // in-register argmax over probs, ascending element order, strict >
    // (first-index-wins == jnp.argmax). Start = class 0 (elem 5 = f1.y).
    float bv = f1.y; int bc = 0;
    if (f1.z > bv) { bv = f1.z; bc = 1; }
    if (f1.w > bv) { bv = f1.w; bc = 2; }
    #pragma unroll
    for (int j = 2; j <= 20; j++) {
        float4 f = p4[j];
        const int b0 = 4 * j - 5;
        if (f.x > bv) { bv = f.x; bc = b0; }
        if (f.y > bv) { bv = f.y; bc = b0 + 1; }
        if (f.z > bv) { bv = f.z; bc = b0 + 2; }
        if (f.w > bv) { bv = f.w; bc = b0 + 3; }
    }
    {
        float e84 = p[84];                 // elem 84 scalar: no OOB on last row
        if (e84 > bv) { bv = e84; bc = 79; }
    }

    const float score = cf * bv;
    float x  = clip01(f0.x / 416.0f);
    float yy = clip01(f0.y / 416.0f);
    float w  = clip01(f0.z / 416.0f);
    float h  = clip01(f0.w / 416.0f);
    float x1 = clip01(x  - w * 0.5f);
    float y1 = clip01(yy - h * 0.5f);
    float x2 = clip01(x  + w * 0.5f);
    float y2 = clip01(yy + h * 0.5f);
    bool keep = (((x2 - x1) * (y2 - y1)) > 0.0005f) && (score > 0.5f);
    if (keep) {
        int bin = (int)((score - 0.5f) * (2.0f * (float)NBINS));
        bin = min(max(bin, 0), NBINS - 1);
        unsigned int pos = atomicAdd(&ws[WS_CNT + bin], 1u);
        if (pos < (unsigned int)CAP) {
            uint2* bucket = (uint2*)&ws[WS_BUCKET];
            bucket[bin * CAP + pos] =
                make_uint2(__float_as_uint(score), (unsigned int)row);
        }
    }
    if (row == 0) {
        float* r0 = (float*)&ws[WS_ROW0];
        r0[0] = score; r0[1] = (float)bc;
        r0[2] = x1; r0[3] = y1; r0[4] = x2; r0[5] = y2;
    }
}

__global__ __launch_bounds__(256) void nms_kernel(
    const float* __restrict__ y, unsigned int* __restrict__ ws,
    float* __restrict__ out)
{
    __shared__ unsigned int chunk[256];
    __shared__ unsigned int fine[32];
    __shared__ unsigned long long keys[SELCAP];
    __shared__ float4 sboxes[SELCAP];
    __shared__ int s_coarse;
    __shared__ int s_bstar;
    __shared__ unsigned int s_m;
    __shared__ int s_picks;
    __shared__ unsigned int s_idx[10];
    __shared__ float s_score[10];
    __shared__ float4 s_box[10];
    __shared__ int s_cls[10];

    const int t = threadIdx.x;
    const uint2* bucket = (const uint2*)&ws[WS_BUCKET];

    // ---- per-chunk clamped counts (32 bins per thread, vectorized)
    unsigned int ssum = 0;
    {
        const uint4* cnt4 = (const uint4*)&ws[WS_CNT];
        #pragma unroll
        for (int i = 0; i < 8; i++) {
            uint4 v = cnt4[t * 8 + i];
            ssum += min(v.x, (unsigned int)CAP) + min(v.y, (unsigned int)CAP)
                  + min(v.z, (unsigned int)CAP) + min(v.w, (unsigned int)CAP);
        }
    }
    chunk[t] = ssum;
    for (int i = t; i < SELCAP; i += 256) keys[i] = 0ull;
    if (t == 0) s_m = 0u;
    __syncthreads();

    // ---- parallel suffix sum over the 256 chunks (Hillis-Steele)
    for (int off = 1; off < 256; off <<= 1) {
        unsigned int v = chunk[t];
        unsigned int a = (t + off < 256) ? chunk[t + off] : 0u;
        __syncthreads();
        chunk[t] = v + a;
        __syncthreads();
    }
    const unsigned int total  = chunk[0];
    const unsigned int target = (total < (unsigned int)TOPK) ? total
                                                             : (unsigned int)TOPK;

    if (target > 0) {           // block-uniform branch; barriers inside are legal
        // coarse chunk: largest c with suffix[c] >= target
        if (chunk[t] >= target && (t == 255 || chunk[t + 1] < target))
            s_coarse = t;
        __syncthreads();

        const int cb = s_coarse * 32;
        if (t < 32) fine[t] = min(ws[WS_CNT + cb + t], (unsigned int)CAP);
        __syncthreads();
        for (int off = 1; off < 32; off <<= 1) {
            unsigned int v = 0, a = 0;
            if (t < 32) { v = fine[t]; a = (t + off < 32) ? fine[t + off] : 0u; }
            __syncthreads();
            if (t < 32) fine[t] = v + a;
            __syncthreads();
        }
        const unsigned int base = (s_coarse < 255) ? chunk[s_coarse + 1] : 0u;
        if (t < 32) {
            unsigned int sfx = base + fine[t];
            unsigned int nxt = (t == 31) ? base : base + fine[t + 1];
            if (sfx >= target && nxt < target) s_bstar = cb + t;
        }
    } else {
        if (t == 0) s_bstar = NBINS;
    }
    __syncthreads();

    // ---- gather all entries from bins >= b* (order fixed by the sort below)
    for (int bin = s_bstar + t; bin < NBINS; bin += 256) {
        unsigned int c = ws[WS_CNT + bin];
        if (c > (unsigned int)CAP) c = CAP;
        for (unsigned int j = 0; j < c; j++) {
            uint2 cv = bucket[bin * CAP + j];
            unsigned int pos = atomicAdd(&s_m, 1u);
            if (pos < (unsigned int)SELCAP)
                keys[pos] = ((unsigned long long)cv.x << 32) |
                            (unsigned long long)(0xFFFFFFFFu - cv.y);
        }
    }
    __syncthreads();
    unsigned int M = s_m;
    if (M > (unsigned int)SELCAP) M = SELCAP;

    // ---- bitonic sort, descending: (score desc, idx asc)
    for (int k = 2; k <= SELCAP; k <<= 1) {
        for (int j = k >> 1; j > 0; j >>= 1) {
            for (int i = t; i < SELCAP; i += 256) {
                int ixj = i ^ j;
                if (ixj > i) {
                    unsigned long long a = keys[i], b = keys[ixj];
                    bool descSeg = ((i & k) == 0);
                    if (descSeg ? (a < b) : (a > b)) { keys[i] = b; keys[ixj] = a; }
                }
            }
            __syncthreads();
        }
    }

    // ---- decode boxes for the sorted prefix
    for (int i = t; i < (int)M; i += 256) {
        unsigned int idx = 0xFFFFFFFFu - (unsigned int)(keys[i] & 0xFFFFFFFFull);
        const float* p = y + (size_t)idx * 85;
        float x  = clip01(p[0] / 416.0f);
        float yy = clip01(p[1] / 416.0f);
        float w  = clip01(p[2] / 416.0f);
        float h  = clip01(p[3] / 416.0f);
        sboxes[i] = make_float4(clip01(x - w * 0.5f), clip01(yy - h * 0.5f),
                                clip01(x + w * 0.5f), clip01(yy + h * 0.5f));
    }
    __syncthreads();

    // ---- sequential greedy-NMS scan (exact equivalent of the 10-step argmax loop)
    if (t == 0) {
        int np = 0;
        for (int i = 0; i < (int)M && np < 10; i++) {
            float4 b = sboxes[i];
            bool ok = true;
            for (int kk = 0; kk < np; kk++) {
                float4 r = s_box[kk];
                float ix1 = fmaxf(r.x, b.x);
                float iy1 = fmaxf(r.y, b.y);
                float ix2 = fminf(r.z, b.z);
                float iy2 = fminf(r.w, b.w);
                float inter = fmaxf(ix2 - ix1, 0.0f) * fmaxf(iy2 - iy1, 0.0f);
                float aref = (r.z - r.x) * (r.w - r.y);
                float aall = (b.z - b.x) * (b.w - b.y);
                float iou = inter / (aref + aall - inter + 1e-10f);
                if (iou > 0.45f) { ok = false; break; }
            }
            if (ok) {
                s_box[np] = b;
                s_idx[np] = 0xFFFFFFFFu - (unsigned int)(keys[i] & 0xFFFFFFFFull);
                s_score[np] = __uint_as_float((unsigned int)(keys[i] >> 32));
                np++;
            }
        }
        s_picks = np;
    }
    __syncthreads();

    // ---- class (argmax of 80 probs) for each pick: 16 lanes per pick
    {
        int p = t >> 4, s = t & 15;
        float bv = -1.0f; int bc = 1 << 20;
        if (p < s_picks) {
            const float* pr = y + (size_t)s_idx[p] * 85 + 5;
            #pragma unroll
            for (int kk = 0; kk < 5; kk++) {
                float v = pr[s + 16 * kk];
                int c = s + 16 * kk;
                if (v > bv) { bv = v; bc = c; }
            }
        }
        #pragma unroll
        for (int m = 8; m >= 1; m >>= 1) {
            float ov = __shfl_xor(bv, m, 64);
            int   oc = __shfl_xor(bc, m, 64);
            if (ov > bv || (ov == bv && oc < bc)) { bv = ov; bc = oc; }
        }
        if (p < s_picks && s == 0) s_cls[p] = bc;
    }
    __syncthreads();

    if (t == 0) {
        const float* r0 = (const float*)&ws[WS_ROW0];
        float score0 = r0[0], class0 = r0[1];
        float4 box0 = make_float4(r0[2], r0[3], r0[4], r0[5]);
        for (int kk = 0; kk < 10; kk++) {
            bool v = kk < s_picks;
            float4 b = v ? s_box[kk] : box0;
            out[4 * kk + 0] = b.x;
            out[4 * kk + 1] = b.y;
            out[4 * kk + 2] = b.z;
            out[4 * kk + 3] = b.w;
            out[40 + kk] = v ? s_score[kk] : score0;
            out[50 + kk] = v ? (float)s_cls[kk] : class0;
            out[60 + kk] = v ? 1.0f : 0.0f;
        }
    }
}

extern "C" void kernel_launch(void* const* d_in, const int* in_sizes, int n_in,
                              void* d_out, int out_size, void* d_ws, size_t ws_size,
                              hipStream_t stream)
{
    const float* y = (const float*)d_in[0];
    unsigned int* ws = (unsigned int*)d_ws;

    init_kernel<<<dim3(NBINS / 256), dim3(256), 0, stream>>>(ws);
    decode_kernel<<<dim3((ROWS + 255) / 256), dim3(256), 0, stream>>>(y, ws);
    nms_kernel<<<dim3(1), dim3(256), 0, stream>>>(y, ws, (float*)d_out);
}

// Round 9
// 76.059 us; speedup vs baseline: 1.1185x; 1.1185x over previous
//
#include <hip/hip_runtime.h>

#define ROWS   681408        // 64 * 10647
#define NBINS  8192
#define CAP    64            // bucket capacity per bin
#define TOPK   192
#define SELCAP 256

// ws word offsets
#define WS_NCAND    0        // global candidate count
#define WS_ROW0     4        // 6 floats: score, class, x1,y1,x2,y2
#define WS_CNT      16       // 8192 uints -> words 16..8207 (16B aligned)
#define WS_BUCKET   8448     // uint2[NBINS*CAP] -> 1,048,576 words (4 MB)
#define WS_CAND     1057024  // uint[ROWS] candidate rows

__device__ __forceinline__ float clip01(float v) {
    return fminf(fmaxf(v, 0.0f), 1.0f);
}

__global__ void init_kernel(unsigned int* __restrict__ ws) {
    int i = blockIdx.x * 256 + threadIdx.x;
    if (i < NBINS) ws[WS_CNT + i] = 0u;
    if (i < 4) ws[i] = 0u;
}

// pass 1: conf gate + block-compacted candidate list.
// conf <= 0.5 can never yield score > 0.5 (score = conf * max(probs), probs < 1).
__global__ __launch_bounds__(256) void conf_kernel(
    const float* __restrict__ y, unsigned int* __restrict__ ws,
    unsigned int* __restrict__ cand)
{
    __shared__ unsigned int wcnt[4];
    __shared__ unsigned int wbase[4];

    const int t    = threadIdx.x;
    const int lane = t & 63;
    const int wv   = t >> 6;
    const unsigned int base = blockIdx.x * 1024;
    const unsigned long long below = (1ull << lane) - 1ull;

    unsigned int r[4];
    bool f[4];
    unsigned long long m[4];
    unsigned int c[4];

    #pragma unroll
    for (int k = 0; k < 4; k++) {
        r[k] = base + t + 256 * k;
        bool ok = false;
        if (r[k] < (unsigned int)ROWS) {
            float cf = y[(size_t)r[k] * 85 + 4];
            ok = (cf > 0.5f) || (r[k] == 0);   // row 0 always examined
        }
        f[k] = ok;
        m[k] = __ballot(ok);
        c[k] = (unsigned int)__popcll(m[k]);
    }

    if (lane == 0) wcnt[wv] = c[0] + c[1] + c[2] + c[3];
    __syncthreads();
    if (t == 0) {
        unsigned int tot = wcnt[0] + wcnt[1] + wcnt[2] + wcnt[3];
        unsigned int g = atomicAdd(&ws[WS_NCAND], tot);
        #pragma unroll
        for (int w = 0; w < 4; w++) { wbase[w] = g; g += wcnt[w]; }
    }
    __syncthreads();

    unsigned int off = wbase[wv];
    #pragma unroll
    for (int k = 0; k < 4; k++) {
        if (f[k])
            cand[off + (unsigned int)__popcll(m[k] & below)] = r[k];
        off += c[k];
    }
}

// pass 2: round-7 4-lane/row decode over the candidate list only.
__global__ __launch_bounds__(256) void decode_kernel(
    const float* __restrict__ y, unsigned int* __restrict__ ws,
    const unsigned int* __restrict__ cand)
{
    const unsigned int ncand = ws[WS_NCAND];
    const int t    = threadIdx.x;
    const int lane = t & 63;
    const int wv   = t >> 6;
    const int s    = lane & 3;        // quad slot 0..3
    const int qr   = lane >> 2;       // quad (row) within wave 0..15
    const unsigned int q = blockIdx.x * 64 + wv * 16 + qr;
    if (q >= ncand) return;           // quad-uniform exit

    const unsigned int row = cand[q];
    const float*  p  = y + (size_t)row * 85;
    const float4* p4 = (const float4*)p;   // dword-aligned float4 loads: OK on gfx9+

    // lane s owns float4 indices {s, s+4, s+8, s+12, s+16} = elems 4s+16j..+3
    float4 f0 = p4[s];
    float4 f1 = p4[s + 4];
    float4 f2 = p4[s + 8];
    float4 f3 = p4[s + 12];
    float4 f4v = p4[s + 16];
    // tail elems 80..84: lane0 takes 80..83 (float4 #20), lane1 takes 84
    float4 ft = make_float4(-1.0f, -1.0f, -1.0f, -1.0f);
    float e84 = -1.0f;
    if (s == 0) ft = p4[20];
    if (s == 1) e84 = p[84];

    // per-lane argmax over probs (elems 5..84), ascending order, strict >
    // (first-index-wins = jnp.argmax), then 2-step quad reduce w/ min-class tie-break
    float bv = -1.0f; int bc = 1 << 20;
    {
        const int b0 = 4 * s;
        if (b0 + 0 >= 5 && f0.x > bv) { bv = f0.x; bc = b0 - 5; }
        if (b0 + 1 >= 5 && f0.y > bv) { bv = f0.y; bc = b0 - 4; }
        if (b0 + 2 >= 5 && f0.z > bv) { bv = f0.z; bc = b0 - 3; }
        if (b0 + 3 >= 5 && f0.w > bv) { bv = f0.w; bc = b0 - 2; }
        if (f1.x > bv) { bv = f1.x; bc = b0 + 11; }
        if (f1.y > bv) { bv = f1.y; bc = b0 + 12; }
        if (f1.z > bv) { bv = f1.z; bc = b0 + 13; }
        if (f1.w > bv) { bv = f1.w; bc = b0 + 14; }
        if (f2.x > bv) { bv = f2.x; bc = b0 + 27; }
        if (f2.y > bv) { bv = f2.y; bc = b0 + 28; }
        if (f2.z > bv) { bv = f2.z; bc = b0 + 29; }
        if (f2.w > bv) { bv = f2.w; bc = b0 + 30; }
        if (f3.x > bv) { bv = f3.x; bc = b0 + 43; }
        if (f3.y > bv) { bv = f3.y; bc = b0 + 44; }
        if (f3.z > bv) { bv = f3.z; bc = b0 + 45; }
        if (f3.w > bv) { bv = f3.w; bc = b0 + 46; }
        if (f4v.x > bv) { bv = f4v.x; bc = b0 + 59; }
        if (f4v.y > bv) { bv = f4v.y; bc = b0 + 60; }
        if (f4v.z > bv) { bv = f4v.z; bc = b0 + 61; }
        if (f4v.w > bv) { bv = f4v.w; bc = b0 + 62; }
        if (s == 0) {
            if (ft.x > bv) { bv = ft.x; bc = 75; }
            if (ft.y > bv) { bv = ft.y; bc = 76; }
            if (ft.z > bv) { bv = ft.z; bc = 77; }
            if (ft.w > bv) { bv = ft.w; bc = 78; }
        }
        if (s == 1 && e84 > bv) { bv = e84; bc = 79; }
    }

    #pragma unroll
    for (int m = 1; m <= 2; m <<= 1) {
        float ov = __shfl_xor(bv, m, 64);
        int   oc = __shfl_xor(bc, m, 64);
        if (ov > bv || (ov == bv && oc < bc)) { bv = ov; bc = oc; }
    }

    // conf = elem 4 = quad-lane-1's f0.x
    float cf = __shfl(f0.x, (lane & 60) + 1, 64);

    if (s == 0) {
        float score = cf * bv;
        float x  = clip01(f0.x / 416.0f);
        float yy = clip01(f0.y / 416.0f);
        float w  = clip01(f0.z / 416.0f);
        float h  = clip01(f0.w / 416.0f);
        float x1 = clip01(x  - w * 0.5f);
        float y1 = clip01(yy - h * 0.5f);
        float x2 = clip01(x  + w * 0.5f);
        float y2 = clip01(yy + h * 0.5f);
        bool keep = (((x2 - x1) * (y2 - y1)) > 0.0005f) && (score > 0.5f);
        if (keep) {
            int bin = (int)((score - 0.5f) * (2.0f * (float)NBINS));
            bin = min(max(bin, 0), NBINS - 1);
            unsigned int pos = atomicAdd(&ws[WS_CNT + bin], 1u);
            if (pos < (unsigned int)CAP) {
                uint2* bucket = (uint2*)&ws[WS_BUCKET];
                bucket[bin * CAP + pos] =
                    make_uint2(__float_as_uint(score), row);
            }
        }
        if (row == 0) {
            float* r0 = (float*)&ws[WS_ROW0];
            r0[0] = score; r0[1] = (float)bc;
            r0[2] = x1; r0[3] = y1; r0[4] = x2; r0[5] = y2;
        }
    }
}

__global__ __launch_bounds__(256) void nms_kernel(
    const float* __restrict__ y, unsigned int* __restrict__ ws,
    float* __restrict__ out)
{
    __shared__ unsigned int chunk[256];
    __shared__ unsigned int fine[32];
    __shared__ unsigned long long keys[SELCAP];
    __shared__ float4 sboxes[SELCAP];
    __shared__ int s_coarse;
    __shared__ int s_bstar;
    __shared__ unsigned int s_m;
    __shared__ int s_picks;
    __shared__ unsigned int s_idx[10];
    __shared__ float s_score[10];
    __shared__ float4 s_box[10];
    __shared__ int s_cls[10];

    const int t = threadIdx.x;
    const uint2* bucket = (const uint2*)&ws[WS_BUCKET];

    // ---- per-chunk clamped counts (32 bins per thread, vectorized)
    unsigned int ssum = 0;
    {
        const uint4* cnt4 = (const uint4*)&ws[WS_CNT];
        #pragma unroll
        for (int i = 0; i < 8; i++) {
            uint4 v = cnt4[t * 8 + i];
            ssum += min(v.x, (unsigned int)CAP) + min(v.y, (unsigned int)CAP)
                  + min(v.z, (unsigned int)CAP) + min(v.w, (unsigned int)CAP);
        }
    }
    chunk[t] = ssum;
    for (int i = t; i < SELCAP; i += 256) keys[i] = 0ull;
    if (t == 0) s_m = 0u;
    __syncthreads();

    // ---- parallel suffix sum over the 256 chunks (Hillis-Steele)
    for (int off = 1; off < 256; off <<= 1) {
        unsigned int v = chunk[t];
        unsigned int a = (t + off < 256) ? chunk[t + off] : 0u;
        __syncthreads();
        chunk[t] = v + a;
        __syncthreads();
    }
    const unsigned int total  = chunk[0];
    const unsigned int target = (total < (unsigned int)TOPK) ? total
                                                             : (unsigned int)TOPK;

    if (target > 0) {           // block-uniform branch; barriers inside are legal
        if (chunk[t] >= target && (t == 255 || chunk[t + 1] < target))
            s_coarse = t;
        __syncthreads();

        const int cb = s_coarse * 32;
        if (t < 32) fine[t] = min(ws[WS_CNT + cb + t], (unsigned int)CAP);
        __syncthreads();
        for (int off = 1; off < 32; off <<= 1) {
            unsigned int v = 0, a = 0;
            if (t < 32) { v = fine[t]; a = (t + off < 32) ? fine[t + off] : 0u; }
            __syncthreads();
            if (t < 32) fine[t] = v + a;
            __syncthreads();
        }
        const unsigned int base = (s_coarse < 255) ? chunk[s_coarse + 1] : 0u;
        if (t < 32) {
            unsigned int sfx = base + fine[t];
            unsigned int nxt = (t == 31) ? base : base + fine[t + 1];
            if (sfx >= target && nxt < target) s_bstar = cb + t;
        }
    } else {
        if (t == 0) s_bstar = NBINS;
    }
    __syncthreads();

    // ---- gather all entries from bins >= b*
    for (int bin = s_bstar + t; bin < NBINS; bin += 256) {
        unsigned int c = ws[WS_CNT + bin];
        if (c > (unsigned int)CAP) c = CAP;
        for (unsigned int j = 0; j < c; j++) {
            uint2 cv = bucket[bin * CAP + j];
            unsigned int pos = atomicAdd(&s_m, 1u);
            if (pos < (unsigned int)SELCAP)
                keys[pos] = ((unsigned long long)cv.x << 32) |
                            (unsigned long long)(0xFFFFFFFFu - cv.y);
        }
    }
    __syncthreads();
    unsigned int M = s_m;
    if (M > (unsigned int)SELCAP) M = SELCAP;

    // ---- bitonic sort, descending: (score desc, idx asc)
    for (int k = 2; k <= SELCAP; k <<= 1) {
        for (int j = k >> 1; j > 0; j >>= 1) {
            for (int i = t; i < SELCAP; i += 256) {
                int ixj = i ^ j;
                if (ixj > i) {
                    unsigned long long a = keys[i], b = keys[ixj];
                    bool descSeg = ((i & k) == 0);
                    if (descSeg ? (a < b) : (a > b)) { keys[i] = b; keys[ixj] = a; }
                }
            }
            __syncthreads();
        }
    }

    // ---- decode boxes for the sorted prefix
    for (int i = t; i < (int)M; i += 256) {
        unsigned int idx = 0xFFFFFFFFu - (unsigned int)(keys[i] & 0xFFFFFFFFull);
        const float* p = y + (size_t)idx * 85;
        float x  = clip01(p[0] / 416.0f);
        float yy = clip01(p[1] / 416.0f);
        float w  = clip01(p[2] / 416.0f);
        float h  = clip01(p[3] / 416.0f);
        sboxes[i] = make_float4(clip01(x - w * 0.5f), clip01(yy - h * 0.5f),
                                clip01(x + w * 0.5f), clip01(yy + h * 0.5f));
    }
    __syncthreads();

    // ---- sequential greedy-NMS scan (exact equivalent of the 10-step argmax loop)
    if (t == 0) {
        int np = 0;
        for (int i = 0; i < (int)M && np < 10; i++) {
            float4 b = sboxes[i];
            bool ok = true;
            for (int kk = 0; kk < np; kk++) {
                float4 r = s_box[kk];
                float ix1 = fmaxf(r.x, b.x);
                float iy1 = fmaxf(r.y, b.y);
                float ix2 = fminf(r.z, b.z);
                float iy2 = fminf(r.w, b.w);
                float inter = fmaxf(ix2 - ix1, 0.0f) * fmaxf(iy2 - iy1, 0.0f);
                float aref = (r.z - r.x) * (r.w - r.y);
                float aall = (b.z - b.x) * (b.w - b.y);
                float iou = inter / (aref + aall - inter + 1e-10f);
                if (iou > 0.45f) { ok = false; break; }
            }
            if (ok) {
                s_box[np] = b;
                s_idx[np] = 0xFFFFFFFFu - (unsigned int)(keys[i] & 0xFFFFFFFFull);
                s_score[np] = __uint_as_float((unsigned int)(keys[i] >> 32));
                np++;
            }
        }
        s_picks = np;
    }
    __syncthreads();

    // ---- class (argmax of 80 probs) for each pick: 16 lanes per pick
    {
        int p = t >> 4, s = t & 15;
        float bv = -1.0f; int bc = 1 << 20;
        if (p < s_picks) {
            const float* pr = y + (size_t)s_idx[p] * 85 + 5;
            #pragma unroll
            for (int kk = 0; kk < 5; kk++) {
                float v = pr[s + 16 * kk];
                int c = s + 16 * kk;
                if (v > bv) { bv = v; bc = c; }
            }
        }
        #pragma unroll
        for (int m = 8; m >= 1; m >>= 1) {
            float ov = __shfl_xor(bv, m, 64);
            int   oc = __shfl_xor(bc, m, 64);
            if (ov > bv || (ov == bv && oc < bc)) { bv = ov; bc = oc; }
        }
        if (p < s_picks && s == 0) s_cls[p] = bc;
    }
    __syncthreads();

    if (t == 0) {
        const float* r0 = (const float*)&ws[WS_ROW0];
        float score0 = r0[0], class0 = r0[1];
        float4 box0 = make_float4(r0[2], r0[3], r0[4], r0[5]);
        for (int kk = 0; kk < 10; kk++) {
            bool v = kk < s_picks;
            float4 b = v ? s_box[kk] : box0;
            out[4 * kk + 0] = b.x;
            out[4 * kk + 1] = b.y;
            out[4 * kk + 2] = b.z;
            out[4 * kk + 3] = b.w;
            out[40 + kk] = v ? s_score[kk] : score0;
            out[50 + kk] = v ? (float)s_cls[kk] : class0;
            out[60 + kk] = v ? 1.0f : 0.0f;
        }
    }
}

extern "C" void kernel_launch(void* const* d_in, const int* in_sizes, int n_in,
                              void* d_out, int out_size, void* d_ws, size_t ws_size,
                              hipStream_t stream)
{
    const float* y = (const float*)d_in[0];
    unsigned int* ws = (unsigned int*)d_ws;
    unsigned int* cand = ws + WS_CAND;

    init_kernel<<<dim3(NBINS / 256), dim3(256), 0, stream>>>(ws);
    conf_kernel<<<dim3((ROWS + 1023) / 1024), dim3(256), 0, stream>>>(y, ws, cand);
    decode_kernel<<<dim3((ROWS + 63) / 64), dim3(256), 0, stream>>>(y, ws, cand);
    nms_kernel<<<dim3(1), dim3(256), 0, stream>>>(y, ws, (float*)d_out);
}